// Round 5
// baseline (237.720 us; speedup 1.0000x reference)
//
#include <hip/hip_runtime.h>

// DicepolyTopk: dice loss + mean of top-10% poly1-BCE values over N=16.7M fp32.
// R9: boundary-overhead attack. R8 budget: kernels ~117us vs wall 207.8us ->
// ~20us per dispatch boundary (R5 corroborates: 1 dispatch => wall==kernel).
// Changes vs R8 (207.8us):
//  - select1 folded into pass2: block 0 runs the R6-proven embedded select1,
//    publishes (done|b1) in ONE u32 via __hip_atomic_store(RELEASE, AGENT);
//    other blocks poll with __hip_atomic_load(ACQUIRE, AGENT) + s_sleep.
//    NO fences, NO same-address RMW (R7's poison was fence+RMW per block).
//    Deadlock-safe: grid clamped to resident capacity via occupancy API.
//  - G2 = capacity (<=1536): R8's G2=2048 over 6-blocks/CU residency (25.6KB
//    LDS) made a 512-block tail wave = +5us. 5 nodes -> 4 nodes.
//  - pass1 unchanged (lane-parity u16-packed LDS hist replication dropped it
//    below pass2: all R8 top-5 were pass2 -> pass1 < 53.2us).

#define NBINS 4096
#define NREP1 8
#define NREP2 4
#define G1 2048
#define G2MAX 1536
#define POLY_EPS 3.1f
#define LN2F 0.69314718056f

struct Ctl {
  unsigned int pub;  // bit31 = done, bits 11:0 = b1  (zeroed by memset)
  unsigned int r;    // k - count(strictly greater L1 buckets), for sel2fin
  unsigned int pad[14];
};

// bce in log2 domain: a2=log2(p), b2=log2(1-p); bce2 = -(b2 + t*(a2-b2))
// bce = bce2*ln2 ; pt = 2^(-bce2) ; poly1 = bce + (1-pt)*eps, clamped >= 0.
__device__ __forceinline__ float poly1_val(float p, float t) {
  float a2 = __builtin_amdgcn_logf(p);         // v_log_f32: log2(p)
  float b2 = __builtin_amdgcn_logf(1.0f - p);  // log2(1-p)
  float bce2 = -(b2 + t * (a2 - b2));
  float pt = __builtin_amdgcn_exp2f(-bce2);    // v_exp_f32: 2^(-bce2)
  float v = bce2 * LN2F + (1.0f - pt) * POLY_EPS;
  return v > 0.0f ? v : 0.0f;
}

// ---------------- pass 1: dice sums + L1 histogram -------------------------
__global__ void __launch_bounds__(256) pass1_kernel(
    const float* __restrict__ preds, const float* __restrict__ gts,
    long long n, double* __restrict__ blockSums,
    unsigned int* __restrict__ hist1R) {
  // 2 replicas (lane parity) x 2048 words; word = replica*2048 + (bin>>1),
  // halfword = bin&1. 16KB total. Per-block elems 8192 < 65535: no overflow.
  __shared__ unsigned int hp[NBINS];
  __shared__ double wred[4][3];
  const int t = threadIdx.x;
  for (int i = t; i < NBINS; i += 256) hp[i] = 0u;
  __syncthreads();
  const unsigned rep = (unsigned)(t & 1) << 11;  // 0 or 2048

  float fI = 0.f, fSp = 0.f, fSt = 0.f;
  const long long n4 = n >> 2;
  const float4* p4 = (const float4*)preds;
  const float4* t4 = (const float4*)gts;
  const long long NT = (long long)G1 * 256;
  const long long gtid = (long long)blockIdx.x * 256 + t;

#define PROC1(pp, tt)                                          \
  do {                                                         \
    float _p = (pp), _t = (tt);                                \
    fI += _p * _t;                                             \
    fSp += _p;                                                 \
    fSt += _t;                                                 \
    float _v = poly1_val(_p, _t);                              \
    unsigned _b = __float_as_uint(_v) >> 19;                   \
    atomicAdd(&hp[rep + (_b >> 1)], (_b & 1u) ? 0x10000u : 1u);\
  } while (0)
#define PROC1V(P, T) \
  do { PROC1(P.x, T.x); PROC1(P.y, T.y); PROC1(P.z, T.z); PROC1(P.w, T.w); } while (0)

  for (long long i = gtid; i < n4; i += 4 * NT) {
    long long i1 = i + NT, i2 = i + 2 * NT, i3 = i + 3 * NT;
    bool g1 = i1 < n4, g2 = i2 < n4, g3 = i3 < n4;
    float4 P0 = p4[i], T0 = t4[i];
    float4 P1, T1, P2, T2, P3, T3;
    if (g1) { P1 = p4[i1]; T1 = t4[i1]; }
    if (g2) { P2 = p4[i2]; T2 = t4[i2]; }
    if (g3) { P3 = p4[i3]; T3 = t4[i3]; }
    PROC1V(P0, T0);
    if (g1) PROC1V(P1, T1);
    if (g2) PROC1V(P2, T2);
    if (g3) PROC1V(P3, T3);
  }
  for (long long e = (n4 << 2) + gtid; e < n; e += NT) PROC1(preds[e], gts[e]);
#undef PROC1V
#undef PROC1

  double dI = fI, dSp = fSp, dSt = fSt;
#pragma unroll
  for (int off = 32; off; off >>= 1) {
    dI += __shfl_down(dI, off, 64);
    dSp += __shfl_down(dSp, off, 64);
    dSt += __shfl_down(dSt, off, 64);
  }
  if ((t & 63) == 0) {
    int w = t >> 6;
    wred[w][0] = dI; wred[w][1] = dSp; wred[w][2] = dSt;
  }
  __syncthreads();
  if (t == 0) {
    double a = 0, b = 0, c = 0;
#pragma unroll
    for (int w = 0; w < 4; ++w) { a += wred[w][0]; b += wred[w][1]; c += wred[w][2]; }
    blockSums[blockIdx.x * 3 + 0] = a;
    blockSums[blockIdx.x * 3 + 1] = b;
    blockSums[blockIdx.x * 3 + 2] = c;
  }

  // merge replicas+halves, flush to one of NREP1 global replica histograms
  unsigned int* dst = hist1R + (size_t)(blockIdx.x & (NREP1 - 1)) * NBINS;
  for (int i = t; i < 2048; i += 256) {
    unsigned a = hp[i], b = hp[i + 2048];
    unsigned c0 = (a & 0xFFFFu) + (b & 0xFFFFu);
    unsigned c1 = (a >> 16) + (b >> 16);
    if (c0) atomicAdd(&dst[2 * i + 0], c0);
    if (c1) atomicAdd(&dst[2 * i + 1], c1);
  }
}

// ---------------- pass 2: embedded select1 + sum>b1 + refine in b1 ---------
__global__ void __launch_bounds__(256) pass2_kernel(
    const float* __restrict__ preds, const float* __restrict__ gts,
    long long n, unsigned int K, const unsigned int* __restrict__ hist1R,
    Ctl* __restrict__ ctl, double* __restrict__ blockSgt,
    unsigned int* __restrict__ hist2R, float* __restrict__ sum2R) {
  __shared__ unsigned int hp[NBINS / 2];  // u16-packed fine counts (8KB)
  __shared__ float s[NBINS];              // fine f32 sums (16KB)
  __shared__ unsigned int chunk[256];
  __shared__ double wred[4];
  __shared__ unsigned int sB1;
  const int t = threadIdx.x;

  for (int i = t; i < NBINS / 2; i += 256) hp[i] = 0u;
  for (int i = t; i < NBINS; i += 256) s[i] = 0.f;

  if (blockIdx.x == 0) {
    // ---- select1 (once, R6-proven): bins [t*16, t*16+16) ----
    unsigned loc[16];
    unsigned tot = 0;
#pragma unroll
    for (int q = 0; q < 4; ++q) {
      uint4 acc = {0u, 0u, 0u, 0u};
      for (int r = 0; r < NREP1; ++r) {
        uint4 v = *(const uint4*)&hist1R[(size_t)r * NBINS + t * 16 + q * 4];
        acc.x += v.x; acc.y += v.y; acc.z += v.z; acc.w += v.w;
      }
      loc[q * 4 + 0] = acc.x; loc[q * 4 + 1] = acc.y;
      loc[q * 4 + 2] = acc.z; loc[q * 4 + 3] = acc.w;
      tot += acc.x + acc.y + acc.z + acc.w;
    }
    chunk[t] = tot;
    __syncthreads();
    for (int off = 1; off < 256; off <<= 1) {  // suffix scan
      unsigned add = (t + off < 256) ? chunk[t + off] : 0u;
      __syncthreads();
      chunk[t] += add;
      __syncthreads();
    }
    unsigned cum = (t < 255) ? chunk[t + 1] : 0u;  // count of bins > t*16+15
    for (int j = 15; j >= 0; --j) {
      unsigned nc = cum + loc[j];
      if (cum < K && nc >= K) {  // exactly one (t,j) globally satisfies this
        sB1 = (unsigned)(t * 16 + j);
        ctl->r = K - cum;  // plain store; read by sel2fin next dispatch
      }
      cum = nc;
    }
    __syncthreads();  // sB1 written
    if (t == 0)
      __hip_atomic_store(&ctl->pub, 0x80000000u | sB1, __ATOMIC_RELEASE,
                         __HIP_MEMORY_SCOPE_AGENT);
  } else {
    // ---- poll for b1: acquire LOADS only (no RMW, no fence) ----
    if (t == 0) {
      unsigned v;
      for (;;) {
        v = __hip_atomic_load(&ctl->pub, __ATOMIC_ACQUIRE,
                              __HIP_MEMORY_SCOPE_AGENT);
        if (v & 0x80000000u) break;
        __builtin_amdgcn_s_sleep(32);  // ~2k cycles between polls
      }
      sB1 = v & 0xFFFu;
    }
  }
  __syncthreads();  // covers hp/s zeroing + sB1 publication (both paths)
  const unsigned b1v = sB1;

  double sgt = 0.0;
  const long long n4 = n >> 2;
  const float4* p4 = (const float4*)preds;
  const float4* t4 = (const float4*)gts;
  const long long NT = (long long)gridDim.x * 256;
  const long long gtid = (long long)blockIdx.x * 256 + t;

#define PROC2(pp, tt)                                        \
  do {                                                       \
    float _v = poly1_val((pp), (tt));                        \
    unsigned _u = __float_as_uint(_v);                       \
    unsigned _b = _u >> 19;                                  \
    if (_b > b1v) {                                          \
      sgt += (double)_v;                                     \
    } else if (_b == b1v) {                                  \
      unsigned _k = (_u >> 7) & 0xFFFu;                      \
      atomicAdd(&hp[_k >> 1], (_k & 1u) ? 0x10000u : 1u);    \
      atomicAdd(&s[_k], _v);                                 \
    }                                                        \
  } while (0)
#define PROC2V(P, T) \
  do { PROC2(P.x, T.x); PROC2(P.y, T.y); PROC2(P.z, T.z); PROC2(P.w, T.w); } while (0)

  for (long long i = gtid; i < n4; i += 4 * NT) {
    long long i1 = i + NT, i2 = i + 2 * NT, i3 = i + 3 * NT;
    bool g1 = i1 < n4, g2 = i2 < n4, g3 = i3 < n4;
    float4 P0 = p4[i], T0 = t4[i];
    float4 P1, T1, P2, T2, P3, T3;
    if (g1) { P1 = p4[i1]; T1 = t4[i1]; }
    if (g2) { P2 = p4[i2]; T2 = t4[i2]; }
    if (g3) { P3 = p4[i3]; T3 = t4[i3]; }
    PROC2V(P0, T0);
    if (g1) PROC2V(P1, T1);
    if (g2) PROC2V(P2, T2);
    if (g3) PROC2V(P3, T3);
  }
  for (long long e = (n4 << 2) + gtid; e < n; e += NT) PROC2(preds[e], gts[e]);
#undef PROC2V
#undef PROC2

#pragma unroll
  for (int off = 32; off; off >>= 1) sgt += __shfl_down(sgt, off, 64);
  if ((t & 63) == 0) wred[t >> 6] = sgt;
  __syncthreads();
  if (t == 0) blockSgt[blockIdx.x] = wred[0] + wred[1] + wred[2] + wred[3];

  unsigned int* hd = hist2R + (size_t)(blockIdx.x & (NREP2 - 1)) * NBINS;
  float* sd = sum2R + (size_t)(blockIdx.x & (NREP2 - 1)) * NBINS;
  for (int i = t; i < NBINS / 2; i += 256) {
    unsigned pw = hp[i];
    unsigned c0 = pw & 0xFFFFu, c1 = pw >> 16;
    if (c0) atomicAdd(&hd[2 * i + 0], c0);
    if (c1) atomicAdd(&hd[2 * i + 1], c1);
  }
  for (int i = t; i < NBINS; i += 256) {
    float sv = s[i];
    if (sv != 0.f) atomicAdd(&sd[i], sv);
  }
}

// ---------------- select2 + finalize: one block ----------------------------
__global__ void __launch_bounds__(1024) sel2fin_kernel(
    const Ctl* __restrict__ ctl, const unsigned int* __restrict__ hist2R,
    const float* __restrict__ sum2R, const double* __restrict__ blockSums,
    const double* __restrict__ blockSgt, float* __restrict__ out,
    unsigned int K, int g2) {
  __shared__ unsigned int chunk[1024];
  __shared__ double redsA[16], redsB[16], redsC[16];
  __shared__ double wfin[16][4];
  __shared__ unsigned int sb2, sr2;
  const int t = threadIdx.x;
  const unsigned K2 = ctl->r;  // remaining count needed from bucket b1 (>= 1)

  // ---- select2 within bucket b1 (fine bins t*4..t*4+3) ----
  unsigned hl[4];
  float sl[4];
  {
    uint4 hacc = {0u, 0u, 0u, 0u};
    float4 sacc = {0.f, 0.f, 0.f, 0.f};
    for (int r = 0; r < NREP2; ++r) {
      uint4 hv = *(const uint4*)&hist2R[(size_t)r * NBINS + t * 4];
      float4 sv = *(const float4*)&sum2R[(size_t)r * NBINS + t * 4];
      hacc.x += hv.x; hacc.y += hv.y; hacc.z += hv.z; hacc.w += hv.w;
      sacc.x += sv.x; sacc.y += sv.y; sacc.z += sv.z; sacc.w += sv.w;
    }
    hl[0] = hacc.x; hl[1] = hacc.y; hl[2] = hacc.z; hl[3] = hacc.w;
    sl[0] = sacc.x; sl[1] = sacc.y; sl[2] = sacc.z; sl[3] = sacc.w;
    chunk[t] = hacc.x + hacc.y + hacc.z + hacc.w;
  }
  __syncthreads();
  for (int off = 1; off < 1024; off <<= 1) {
    unsigned add = (t + off < 1024) ? chunk[t + off] : 0u;
    __syncthreads();
    chunk[t] += add;
    __syncthreads();
  }
  unsigned cum = (t < 1023) ? chunk[t + 1] : 0u;
  for (int j = 3; j >= 0; --j) {
    unsigned nc = cum + hl[j];
    if (cum < K2 && nc >= K2) { sb2 = (unsigned)(t * 4 + j); sr2 = K2 - cum; }
    cum = nc;
  }
  __syncthreads();
  const unsigned b2 = sb2, r2 = sr2;

  // exact sum of sub-buckets strictly above b2; b2's own count/sum
  double loc = 0.0, b2s = 0.0, b2c = 0.0;
#pragma unroll
  for (int j = 0; j < 4; ++j) {
    int bin = t * 4 + j;
    if (bin > (int)b2) loc += (double)sl[j];
    if (bin == (int)b2) { b2s = (double)sl[j]; b2c = (double)hl[j]; }
  }
#pragma unroll
  for (int off = 32; off; off >>= 1) {
    loc += __shfl_down(loc, off, 64);
    b2s += __shfl_down(b2s, off, 64);
    b2c += __shfl_down(b2c, off, 64);
  }
  if ((t & 63) == 0) { int w = t >> 6; redsA[w] = loc; redsB[w] = b2s; redsC[w] = b2c; }

  // ---- finalize: reduce per-block dice partials + Sgt ----
  double I = 0, Sp = 0, St = 0, Sg = 0;
  for (int i = t; i < G1; i += 1024) {
    I += blockSums[i * 3 + 0];
    Sp += blockSums[i * 3 + 1];
    St += blockSums[i * 3 + 2];
  }
  for (int i = t; i < g2; i += 1024) Sg += blockSgt[i];
#pragma unroll
  for (int off = 32; off; off >>= 1) {
    I += __shfl_down(I, off, 64);
    Sp += __shfl_down(Sp, off, 64);
    St += __shfl_down(St, off, 64);
    Sg += __shfl_down(Sg, off, 64);
  }
  if ((t & 63) == 0) {
    int w = t >> 6;
    wfin[w][0] = I; wfin[w][1] = Sp; wfin[w][2] = St; wfin[w][3] = Sg;
  }
  __syncthreads();
  if (t == 0) {
    double S2 = 0, bs = 0, bc = 0, tI = 0, tSp = 0, tSt = 0, tSg = 0;
#pragma unroll
    for (int w = 0; w < 16; ++w) {
      S2 += redsA[w]; bs += redsB[w]; bc += redsC[w];
      tI += wfin[w][0]; tSp += wfin[w][1]; tSt += wfin[w][2]; tSg += wfin[w][3];
    }
    // ties in sub-bucket b2 span < 128 ulps: bin average for the r2 remaining
    double topk_extra = S2 + (double)r2 * (bs / bc);
    double dice = 1.0 - (2.0 * tI + 1.0) / (tSp + tSt + 1.0);
    out[0] = (float)(dice + (tSg + topk_extra) / (double)K);
  }
}

extern "C" void kernel_launch(void* const* d_in, const int* in_sizes, int n_in,
                              void* d_out, int out_size, void* d_ws,
                              size_t ws_size, hipStream_t stream) {
  (void)n_in; (void)out_size; (void)ws_size;
  const float* preds = (const float*)d_in[0];
  const float* gts = (const float*)d_in[1];
  long long n = (long long)in_sizes[0];
  unsigned int K = (unsigned int)(n * 10 / 100);  // matches int(N*10/100)

  char* ws = (char*)d_ws;
  double* blockSums = (double*)ws;                     // G1*3*8 = 49152
  double* blockSgt = (double*)(ws + 49152);            // G2MAX*8 = 12288 -> 61440
  Ctl* ctl = (Ctl*)(ws + 61440);                       // 64B, in zeroed region
  unsigned int* hist1R = (unsigned int*)(ws + 61504);  // NREP1*NBINS*4 = 131072
  unsigned int* hist2R = (unsigned int*)(ws + 192576); // NREP2*NBINS*4 = 65536
  float* sum2R = (float*)(ws + 258112);                // 65536 -> end 323648

  // pass2 grid = resident capacity (occupancy API) so block 0 is always
  // scheduled while others poll; clamp to blockSgt size.
  static int s_g2 = 0;
  if (s_g2 == 0) {
    int nb = 0;
    if (hipOccupancyMaxActiveBlocksPerMultiprocessor(&nb, pass2_kernel, 256,
                                                     0) != hipSuccess || nb < 1)
      nb = 4;  // conservative fallback (25.6KB LDS can always fit 4/CU)
    int dev = 0;
    (void)hipGetDevice(&dev);
    int ncu = 0;
    if (hipDeviceGetAttribute(&ncu, hipDeviceAttributeMultiprocessorCount,
                              dev) != hipSuccess || ncu <= 0)
      ncu = 256;
    long long g = (long long)nb * ncu;
    if (g > G2MAX) g = G2MAX;
    if (g < 256) g = 256;
    s_g2 = (int)g;
  }

  // zero ctl + replica region (contiguous, 256KB + 64B)
  (void)hipMemsetAsync(ws + 61440, 0, 262208, stream);

  pass1_kernel<<<G1, 256, 0, stream>>>(preds, gts, n, blockSums, hist1R);
  pass2_kernel<<<s_g2, 256, 0, stream>>>(preds, gts, n, K, hist1R, ctl,
                                         blockSgt, hist2R, sum2R);
  sel2fin_kernel<<<1, 1024, 0, stream>>>(ctl, hist2R, sum2R, blockSums,
                                         blockSgt, (float*)d_out, K, s_g2);
}

// Round 6
// 217.549 us; speedup vs baseline: 1.0927x; 1.0927x over previous
//
#include <hip/hip_runtime.h>

// DicepolyTopk: dice loss + mean of top-10% poly1-BCE values over N=16.7M fp32.
// R10: consolidation of the two proven-best components, never before combined:
//  - pass1 = R8's (lane-parity u16-packed replicated LDS hist, f32 accums,
//    16-elem/iter dense strides): measured <53us (was ~90 in R6).
//  - pass2 = R6's structure (embedded REDUNDANT select1 per block -- measured
//    48.4us total in R6, the fastest pass2 ever; no polling/atomics) with
//    R8's dense 4-stride loop and compile-time G2=1536 (6 blocks/CU via
//    25.6KB LDS -> zero tail).
//  - every pass2 block also writes ctl->r (identical value, plain store), so
//    sel2fin needs no hist1R re-derivation.
// R9 lesson encoded here: runtime-valued grid strides + publish/poll atomics
// in the kernel prologue halved the scan loop's issue rate (R5 & R9 both);
// all grids/strides below are compile-time constants, no cross-block comms.
// 4 dispatches: memset(262KB) -> pass1 -> pass2 -> sel2fin.

#define NBINS 4096
#define NREP1 8
#define NREP2 4
#define G1 2048
#define G2 1536
#define POLY_EPS 3.1f
#define LN2F 0.69314718056f

struct Ctl {
  unsigned int r;  // k - count(strictly greater L1 buckets); written by pass2
  unsigned int pad[15];
};

// bce in log2 domain: a2=log2(p), b2=log2(1-p); bce2 = -(b2 + t*(a2-b2))
// bce = bce2*ln2 ; pt = 2^(-bce2) ; poly1 = bce + (1-pt)*eps, clamped >= 0.
__device__ __forceinline__ float poly1_val(float p, float t) {
  float a2 = __builtin_amdgcn_logf(p);         // v_log_f32: log2(p)
  float b2 = __builtin_amdgcn_logf(1.0f - p);  // log2(1-p)
  float bce2 = -(b2 + t * (a2 - b2));
  float pt = __builtin_amdgcn_exp2f(-bce2);    // v_exp_f32: 2^(-bce2)
  float v = bce2 * LN2F + (1.0f - pt) * POLY_EPS;
  return v > 0.0f ? v : 0.0f;
}

// ---------------- pass 1: dice sums + L1 histogram (R8 verbatim) -----------
__global__ void __launch_bounds__(256) pass1_kernel(
    const float* __restrict__ preds, const float* __restrict__ gts,
    long long n, double* __restrict__ blockSums,
    unsigned int* __restrict__ hist1R) {
  // 2 replicas (lane parity) x 2048 words; word = replica*2048 + (bin>>1),
  // halfword = bin&1. 16KB total. Per-block elems 8192 < 65535: no overflow.
  __shared__ unsigned int hp[NBINS];
  __shared__ double wred[4][3];
  const int t = threadIdx.x;
  for (int i = t; i < NBINS; i += 256) hp[i] = 0u;
  __syncthreads();
  const unsigned rep = (unsigned)(t & 1) << 11;  // 0 or 2048

  float fI = 0.f, fSp = 0.f, fSt = 0.f;
  const long long n4 = n >> 2;
  const float4* p4 = (const float4*)preds;
  const float4* t4 = (const float4*)gts;
  const long long NT = (long long)G1 * 256;  // compile-time stride
  const long long gtid = (long long)blockIdx.x * 256 + t;

#define PROC1(pp, tt)                                          \
  do {                                                         \
    float _p = (pp), _t = (tt);                                \
    fI += _p * _t;                                             \
    fSp += _p;                                                 \
    fSt += _t;                                                 \
    float _v = poly1_val(_p, _t);                              \
    unsigned _b = __float_as_uint(_v) >> 19;                   \
    atomicAdd(&hp[rep + (_b >> 1)], (_b & 1u) ? 0x10000u : 1u);\
  } while (0)
#define PROC1V(P, T) \
  do { PROC1(P.x, T.x); PROC1(P.y, T.y); PROC1(P.z, T.z); PROC1(P.w, T.w); } while (0)

  for (long long i = gtid; i < n4; i += 4 * NT) {
    long long i1 = i + NT, i2 = i + 2 * NT, i3 = i + 3 * NT;
    bool g1 = i1 < n4, g2 = i2 < n4, g3 = i3 < n4;
    float4 P0 = p4[i], T0 = t4[i];
    float4 P1, T1, P2, T2, P3, T3;
    if (g1) { P1 = p4[i1]; T1 = t4[i1]; }
    if (g2) { P2 = p4[i2]; T2 = t4[i2]; }
    if (g3) { P3 = p4[i3]; T3 = t4[i3]; }
    PROC1V(P0, T0);
    if (g1) PROC1V(P1, T1);
    if (g2) PROC1V(P2, T2);
    if (g3) PROC1V(P3, T3);
  }
  for (long long e = (n4 << 2) + gtid; e < n; e += NT) PROC1(preds[e], gts[e]);
#undef PROC1V
#undef PROC1

  double dI = fI, dSp = fSp, dSt = fSt;
#pragma unroll
  for (int off = 32; off; off >>= 1) {
    dI += __shfl_down(dI, off, 64);
    dSp += __shfl_down(dSp, off, 64);
    dSt += __shfl_down(dSt, off, 64);
  }
  if ((t & 63) == 0) {
    int w = t >> 6;
    wred[w][0] = dI; wred[w][1] = dSp; wred[w][2] = dSt;
  }
  __syncthreads();
  if (t == 0) {
    double a = 0, b = 0, c = 0;
#pragma unroll
    for (int w = 0; w < 4; ++w) { a += wred[w][0]; b += wred[w][1]; c += wred[w][2]; }
    blockSums[blockIdx.x * 3 + 0] = a;
    blockSums[blockIdx.x * 3 + 1] = b;
    blockSums[blockIdx.x * 3 + 2] = c;
  }

  // merge replicas+halves, flush to one of NREP1 global replica histograms
  unsigned int* dst = hist1R + (size_t)(blockIdx.x & (NREP1 - 1)) * NBINS;
  for (int i = t; i < 2048; i += 256) {
    unsigned a = hp[i], b = hp[i + 2048];
    unsigned c0 = (a & 0xFFFFu) + (b & 0xFFFFu);
    unsigned c1 = (a >> 16) + (b >> 16);
    if (c0) atomicAdd(&dst[2 * i + 0], c0);
    if (c1) atomicAdd(&dst[2 * i + 1], c1);
  }
}

// ---------------- pass 2: embedded select1 (R6-proven) + sum>b1 + refine ---
__global__ void __launch_bounds__(256) pass2_kernel(
    const float* __restrict__ preds, const float* __restrict__ gts,
    long long n, unsigned int K, const unsigned int* __restrict__ hist1R,
    Ctl* __restrict__ ctl, double* __restrict__ blockSgt,
    unsigned int* __restrict__ hist2R, float* __restrict__ sum2R) {
  __shared__ unsigned int hp[NBINS / 2];  // u16-packed fine counts (8KB)
  __shared__ float s[NBINS];              // fine f32 sums (16KB)
  __shared__ unsigned int chunk[256];
  __shared__ double wred[4];
  __shared__ unsigned int sB1;
  const int t = threadIdx.x;

  // ---- select1, redundant per block (R6-proven fast: replicas hit L2) ----
  {
    unsigned loc[16];
    unsigned tot = 0;
#pragma unroll
    for (int q = 0; q < 4; ++q) {
      uint4 acc = {0u, 0u, 0u, 0u};
      for (int r = 0; r < NREP1; ++r) {
        uint4 v = *(const uint4*)&hist1R[(size_t)r * NBINS + t * 16 + q * 4];
        acc.x += v.x; acc.y += v.y; acc.z += v.z; acc.w += v.w;
      }
      loc[q * 4 + 0] = acc.x; loc[q * 4 + 1] = acc.y;
      loc[q * 4 + 2] = acc.z; loc[q * 4 + 3] = acc.w;
      tot += acc.x + acc.y + acc.z + acc.w;
    }
    chunk[t] = tot;
    __syncthreads();
    for (int off = 1; off < 256; off <<= 1) {  // suffix scan
      unsigned add = (t + off < 256) ? chunk[t + off] : 0u;
      __syncthreads();
      chunk[t] += add;
      __syncthreads();
    }
    unsigned cum = (t < 255) ? chunk[t + 1] : 0u;  // count of bins > t*16+15
    for (int j = 15; j >= 0; --j) {
      unsigned nc = cum + loc[j];
      if (cum < K && nc >= K) {  // exactly one (t,j) globally satisfies this
        sB1 = (unsigned)(t * 16 + j);
        ctl->r = K - cum;  // same value from every block: benign plain store
      }
      cum = nc;
    }
  }
  for (int i = t; i < NBINS / 2; i += 256) hp[i] = 0u;
  for (int i = t; i < NBINS; i += 256) s[i] = 0.f;
  __syncthreads();  // publishes sB1 + zeroed LDS
  const unsigned b1v = sB1;

  double sgt = 0.0;
  const long long n4 = n >> 2;
  const float4* p4 = (const float4*)preds;
  const float4* t4 = (const float4*)gts;
  const long long NT = (long long)G2 * 256;  // compile-time stride
  const long long gtid = (long long)blockIdx.x * 256 + t;

#define PROC2(pp, tt)                                        \
  do {                                                       \
    float _v = poly1_val((pp), (tt));                        \
    unsigned _u = __float_as_uint(_v);                       \
    unsigned _b = _u >> 19;                                  \
    if (_b > b1v) {                                          \
      sgt += (double)_v;                                     \
    } else if (_b == b1v) {                                  \
      unsigned _k = (_u >> 7) & 0xFFFu;                      \
      atomicAdd(&hp[_k >> 1], (_k & 1u) ? 0x10000u : 1u);    \
      atomicAdd(&s[_k], _v);                                 \
    }                                                        \
  } while (0)
#define PROC2V(P, T) \
  do { PROC2(P.x, T.x); PROC2(P.y, T.y); PROC2(P.z, T.z); PROC2(P.w, T.w); } while (0)

  for (long long i = gtid; i < n4; i += 4 * NT) {
    long long i1 = i + NT, i2 = i + 2 * NT, i3 = i + 3 * NT;
    bool g1 = i1 < n4, g2 = i2 < n4, g3 = i3 < n4;
    float4 P0 = p4[i], T0 = t4[i];
    float4 P1, T1, P2, T2, P3, T3;
    if (g1) { P1 = p4[i1]; T1 = t4[i1]; }
    if (g2) { P2 = p4[i2]; T2 = t4[i2]; }
    if (g3) { P3 = p4[i3]; T3 = t4[i3]; }
    PROC2V(P0, T0);
    if (g1) PROC2V(P1, T1);
    if (g2) PROC2V(P2, T2);
    if (g3) PROC2V(P3, T3);
  }
  for (long long e = (n4 << 2) + gtid; e < n; e += NT) PROC2(preds[e], gts[e]);
#undef PROC2V
#undef PROC2

#pragma unroll
  for (int off = 32; off; off >>= 1) sgt += __shfl_down(sgt, off, 64);
  if ((t & 63) == 0) wred[t >> 6] = sgt;
  __syncthreads();
  if (t == 0) blockSgt[blockIdx.x] = wred[0] + wred[1] + wred[2] + wred[3];

  unsigned int* hd = hist2R + (size_t)(blockIdx.x & (NREP2 - 1)) * NBINS;
  float* sd = sum2R + (size_t)(blockIdx.x & (NREP2 - 1)) * NBINS;
  for (int i = t; i < NBINS / 2; i += 256) {
    unsigned pw = hp[i];
    unsigned c0 = pw & 0xFFFFu, c1 = pw >> 16;
    if (c0) atomicAdd(&hd[2 * i + 0], c0);
    if (c1) atomicAdd(&hd[2 * i + 1], c1);
  }
  for (int i = t; i < NBINS; i += 256) {
    float sv = s[i];
    if (sv != 0.f) atomicAdd(&sd[i], sv);
  }
}

// ---------------- select2 + finalize: one block ----------------------------
__global__ void __launch_bounds__(1024) sel2fin_kernel(
    const Ctl* __restrict__ ctl, const unsigned int* __restrict__ hist2R,
    const float* __restrict__ sum2R, const double* __restrict__ blockSums,
    const double* __restrict__ blockSgt, float* __restrict__ out,
    unsigned int K) {
  __shared__ unsigned int chunk[1024];
  __shared__ double redsA[16], redsB[16], redsC[16];
  __shared__ double wfin[16][4];
  __shared__ unsigned int sb2, sr2;
  const int t = threadIdx.x;
  const unsigned K2 = ctl->r;  // remaining count needed from bucket b1 (>= 1)

  // ---- select2 within bucket b1 (fine bins t*4..t*4+3) ----
  unsigned hl[4];
  float sl[4];
  {
    uint4 hacc = {0u, 0u, 0u, 0u};
    float4 sacc = {0.f, 0.f, 0.f, 0.f};
    for (int r = 0; r < NREP2; ++r) {
      uint4 hv = *(const uint4*)&hist2R[(size_t)r * NBINS + t * 4];
      float4 sv = *(const float4*)&sum2R[(size_t)r * NBINS + t * 4];
      hacc.x += hv.x; hacc.y += hv.y; hacc.z += hv.z; hacc.w += hv.w;
      sacc.x += sv.x; sacc.y += sv.y; sacc.z += sv.z; sacc.w += sv.w;
    }
    hl[0] = hacc.x; hl[1] = hacc.y; hl[2] = hacc.z; hl[3] = hacc.w;
    sl[0] = sacc.x; sl[1] = sacc.y; sl[2] = sacc.z; sl[3] = sacc.w;
    chunk[t] = hacc.x + hacc.y + hacc.z + hacc.w;
  }
  __syncthreads();
  for (int off = 1; off < 1024; off <<= 1) {
    unsigned add = (t + off < 1024) ? chunk[t + off] : 0u;
    __syncthreads();
    chunk[t] += add;
    __syncthreads();
  }
  unsigned cum = (t < 1023) ? chunk[t + 1] : 0u;
  for (int j = 3; j >= 0; --j) {
    unsigned nc = cum + hl[j];
    if (cum < K2 && nc >= K2) { sb2 = (unsigned)(t * 4 + j); sr2 = K2 - cum; }
    cum = nc;
  }
  __syncthreads();
  const unsigned b2 = sb2, r2 = sr2;

  // exact sum of sub-buckets strictly above b2; b2's own count/sum
  double loc = 0.0, b2s = 0.0, b2c = 0.0;
#pragma unroll
  for (int j = 0; j < 4; ++j) {
    int bin = t * 4 + j;
    if (bin > (int)b2) loc += (double)sl[j];
    if (bin == (int)b2) { b2s = (double)sl[j]; b2c = (double)hl[j]; }
  }
#pragma unroll
  for (int off = 32; off; off >>= 1) {
    loc += __shfl_down(loc, off, 64);
    b2s += __shfl_down(b2s, off, 64);
    b2c += __shfl_down(b2c, off, 64);
  }
  if ((t & 63) == 0) { int w = t >> 6; redsA[w] = loc; redsB[w] = b2s; redsC[w] = b2c; }

  // ---- finalize: reduce per-block dice partials + Sgt ----
  double I = 0, Sp = 0, St = 0, Sg = 0;
  for (int i = t; i < G1; i += 1024) {
    I += blockSums[i * 3 + 0];
    Sp += blockSums[i * 3 + 1];
    St += blockSums[i * 3 + 2];
  }
  for (int i = t; i < G2; i += 1024) Sg += blockSgt[i];
#pragma unroll
  for (int off = 32; off; off >>= 1) {
    I += __shfl_down(I, off, 64);
    Sp += __shfl_down(Sp, off, 64);
    St += __shfl_down(St, off, 64);
    Sg += __shfl_down(Sg, off, 64);
  }
  if ((t & 63) == 0) {
    int w = t >> 6;
    wfin[w][0] = I; wfin[w][1] = Sp; wfin[w][2] = St; wfin[w][3] = Sg;
  }
  __syncthreads();
  if (t == 0) {
    double S2 = 0, bs = 0, bc = 0, tI = 0, tSp = 0, tSt = 0, tSg = 0;
#pragma unroll
    for (int w = 0; w < 16; ++w) {
      S2 += redsA[w]; bs += redsB[w]; bc += redsC[w];
      tI += wfin[w][0]; tSp += wfin[w][1]; tSt += wfin[w][2]; tSg += wfin[w][3];
    }
    // ties in sub-bucket b2 span < 128 ulps: bin average for the r2 remaining
    double topk_extra = S2 + (double)r2 * (bs / bc);
    double dice = 1.0 - (2.0 * tI + 1.0) / (tSp + tSt + 1.0);
    out[0] = (float)(dice + (tSg + topk_extra) / (double)K);
  }
}

extern "C" void kernel_launch(void* const* d_in, const int* in_sizes, int n_in,
                              void* d_out, int out_size, void* d_ws,
                              size_t ws_size, hipStream_t stream) {
  (void)n_in; (void)out_size; (void)ws_size;
  const float* preds = (const float*)d_in[0];
  const float* gts = (const float*)d_in[1];
  long long n = (long long)in_sizes[0];
  unsigned int K = (unsigned int)(n * 10 / 100);  // matches int(N*10/100)

  char* ws = (char*)d_ws;
  double* blockSums = (double*)ws;                     // G1*3*8 = 49152
  double* blockSgt = (double*)(ws + 49152);            // G2*8 = 12288 -> 61440
  Ctl* ctl = (Ctl*)(ws + 61440);                       // 64B, in zeroed region
  unsigned int* hist1R = (unsigned int*)(ws + 61504);  // NREP1*NBINS*4 = 131072
  unsigned int* hist2R = (unsigned int*)(ws + 192576); // NREP2*NBINS*4 = 65536
  float* sum2R = (float*)(ws + 258112);                // 65536 -> end 323648

  // zero ctl + replica region (contiguous, 256KB + 64B)
  (void)hipMemsetAsync(ws + 61440, 0, 262208, stream);

  pass1_kernel<<<G1, 256, 0, stream>>>(preds, gts, n, blockSums, hist1R);
  pass2_kernel<<<G2, 256, 0, stream>>>(preds, gts, n, K, hist1R, ctl,
                                       blockSgt, hist2R, sum2R);
  sel2fin_kernel<<<1, 1024, 0, stream>>>(ctl, hist2R, sum2R, blockSums,
                                         blockSgt, (float*)d_out, K);
}

// Round 7
// 214.620 us; speedup vs baseline: 1.1076x; 1.0136x over previous
//
#include <hip/hip_runtime.h>

// DicepolyTopk: dice loss + mean of top-10% poly1-BCE values over N=16.7M fp32.
// R11: verbatim-best-of-each-round build (never actually benched together):
//  - pass1 = R8's kernel, UNCHANGED: lane-parity u16-packed replicated LDS
//    hist + f32 accums + 4-stride dense loads. Measured <53us.
//  - pass2 = R6's kernel, UNCHANGED except one plain ctl->r store: embedded
//    redundant select1 + PAIRED float4 loads (lane-contiguous 2KB/wave pair;
//    R10 disproved the "half-coalesced" theory: paired 48.4us beat 4-stride
//    53.4/64.9) + launch_bounds(256,6) + G2=1536 (zero tail).
//  - sel2fin = R10's (reads ctl->r; absmax 0.0 proven).
// 4 nodes: memset(256KB) -> pass1 -> pass2 -> sel2fin. No cross-block
// polling/fences (R7/R9 poison), all grid strides compile-time (R5/R9 lesson).

#define NBINS 4096
#define NREP1 8
#define NREP2 4
#define G1 2048
#define G2 1536
#define POLY_EPS 3.1f
#define LN2F 0.69314718056f

struct Ctl {
  unsigned int r;  // k - count(strictly greater L1 buckets); written by pass2
  unsigned int pad[15];
};

// bce in log2 domain: a2=log2(p), b2=log2(1-p); bce2 = -(b2 + t*(a2-b2))
// bce = bce2*ln2 ; pt = 2^(-bce2) ; poly1 = bce + (1-pt)*eps, clamped >= 0.
__device__ __forceinline__ float poly1_val(float p, float t) {
  float a2 = __builtin_amdgcn_logf(p);         // v_log_f32: log2(p)
  float b2 = __builtin_amdgcn_logf(1.0f - p);  // log2(1-p)
  float bce2 = -(b2 + t * (a2 - b2));
  float pt = __builtin_amdgcn_exp2f(-bce2);    // v_exp_f32: 2^(-bce2)
  float v = bce2 * LN2F + (1.0f - pt) * POLY_EPS;
  return v > 0.0f ? v : 0.0f;
}

// ---------------- pass 1: dice sums + L1 histogram (R8 verbatim) -----------
__global__ void __launch_bounds__(256) pass1_kernel(
    const float* __restrict__ preds, const float* __restrict__ gts,
    long long n, double* __restrict__ blockSums,
    unsigned int* __restrict__ hist1R) {
  // 2 replicas (lane parity) x 2048 words; word = replica*2048 + (bin>>1),
  // halfword = bin&1. 16KB total. Per-block elems 8192 < 65535: no overflow.
  __shared__ unsigned int hp[NBINS];
  __shared__ double wred[4][3];
  const int t = threadIdx.x;
  for (int i = t; i < NBINS; i += 256) hp[i] = 0u;
  __syncthreads();
  const unsigned rep = (unsigned)(t & 1) << 11;  // 0 or 2048

  float fI = 0.f, fSp = 0.f, fSt = 0.f;
  const long long n4 = n >> 2;
  const float4* p4 = (const float4*)preds;
  const float4* t4 = (const float4*)gts;
  const long long NT = (long long)G1 * 256;  // compile-time stride
  const long long gtid = (long long)blockIdx.x * 256 + t;

#define PROC1(pp, tt)                                          \
  do {                                                         \
    float _p = (pp), _t = (tt);                                \
    fI += _p * _t;                                             \
    fSp += _p;                                                 \
    fSt += _t;                                                 \
    float _v = poly1_val(_p, _t);                              \
    unsigned _b = __float_as_uint(_v) >> 19;                   \
    atomicAdd(&hp[rep + (_b >> 1)], (_b & 1u) ? 0x10000u : 1u);\
  } while (0)
#define PROC1V(P, T) \
  do { PROC1(P.x, T.x); PROC1(P.y, T.y); PROC1(P.z, T.z); PROC1(P.w, T.w); } while (0)

  for (long long i = gtid; i < n4; i += 4 * NT) {
    long long i1 = i + NT, i2 = i + 2 * NT, i3 = i + 3 * NT;
    bool g1 = i1 < n4, g2 = i2 < n4, g3 = i3 < n4;
    float4 P0 = p4[i], T0 = t4[i];
    float4 P1, T1, P2, T2, P3, T3;
    if (g1) { P1 = p4[i1]; T1 = t4[i1]; }
    if (g2) { P2 = p4[i2]; T2 = t4[i2]; }
    if (g3) { P3 = p4[i3]; T3 = t4[i3]; }
    PROC1V(P0, T0);
    if (g1) PROC1V(P1, T1);
    if (g2) PROC1V(P2, T2);
    if (g3) PROC1V(P3, T3);
  }
  for (long long e = (n4 << 2) + gtid; e < n; e += NT) PROC1(preds[e], gts[e]);
#undef PROC1V
#undef PROC1

  double dI = fI, dSp = fSp, dSt = fSt;
#pragma unroll
  for (int off = 32; off; off >>= 1) {
    dI += __shfl_down(dI, off, 64);
    dSp += __shfl_down(dSp, off, 64);
    dSt += __shfl_down(dSt, off, 64);
  }
  if ((t & 63) == 0) {
    int w = t >> 6;
    wred[w][0] = dI; wred[w][1] = dSp; wred[w][2] = dSt;
  }
  __syncthreads();
  if (t == 0) {
    double a = 0, b = 0, c = 0;
#pragma unroll
    for (int w = 0; w < 4; ++w) { a += wred[w][0]; b += wred[w][1]; c += wred[w][2]; }
    blockSums[blockIdx.x * 3 + 0] = a;
    blockSums[blockIdx.x * 3 + 1] = b;
    blockSums[blockIdx.x * 3 + 2] = c;
  }

  // merge replicas+halves, flush to one of NREP1 global replica histograms
  unsigned int* dst = hist1R + (size_t)(blockIdx.x & (NREP1 - 1)) * NBINS;
  for (int i = t; i < 2048; i += 256) {
    unsigned a = hp[i], b = hp[i + 2048];
    unsigned c0 = (a & 0xFFFFu) + (b & 0xFFFFu);
    unsigned c1 = (a >> 16) + (b >> 16);
    if (c0) atomicAdd(&dst[2 * i + 0], c0);
    if (c1) atomicAdd(&dst[2 * i + 1], c1);
  }
}

// ---------------- pass 2: R6 verbatim (embedded select1 + paired loads) ----
__global__ void __launch_bounds__(256, 6) pass2_kernel(
    const float* __restrict__ preds, const float* __restrict__ gts,
    long long n, unsigned int K, const unsigned int* __restrict__ hist1R,
    Ctl* __restrict__ ctl, double* __restrict__ blockSgt,
    unsigned int* __restrict__ hist2R, float* __restrict__ sum2R) {
  __shared__ unsigned int hp[NBINS / 2];  // u16-packed fine counts (8KB)
  __shared__ float s[NBINS];              // fine f32 sums (16KB)
  __shared__ unsigned int chunk[256];
  __shared__ double wred[4];
  __shared__ unsigned int sb1;

  const int t = threadIdx.x;

  // ---- select1 (redundant per block, R6-proven): bins [t*16, t*16+16) ----
  {
    unsigned loc[16];
    unsigned tot = 0;
#pragma unroll
    for (int q = 0; q < 4; ++q) {
      uint4 acc = {0u, 0u, 0u, 0u};
      for (int r = 0; r < NREP1; ++r) {
        uint4 v = *(const uint4*)&hist1R[(size_t)r * NBINS + t * 16 + q * 4];
        acc.x += v.x; acc.y += v.y; acc.z += v.z; acc.w += v.w;
      }
      loc[q * 4 + 0] = acc.x; loc[q * 4 + 1] = acc.y;
      loc[q * 4 + 2] = acc.z; loc[q * 4 + 3] = acc.w;
      tot += acc.x + acc.y + acc.z + acc.w;
    }
    chunk[t] = tot;
    __syncthreads();
    for (int off = 1; off < 256; off <<= 1) {  // suffix scan
      unsigned add = (t + off < 256) ? chunk[t + off] : 0u;
      __syncthreads();
      chunk[t] += add;
      __syncthreads();
    }
    unsigned cum = (t < 255) ? chunk[t + 1] : 0u;  // count of bins > t*16+15
    for (int j = 15; j >= 0; --j) {
      unsigned nc = cum + loc[j];
      if (cum < K && nc >= K) {  // exactly one (t,j) globally satisfies this
        sb1 = (unsigned)(t * 16 + j);
        ctl->r = K - cum;  // same value from every block: benign plain store
      }
      cum = nc;
    }
  }
  for (int i = t; i < NBINS / 2; i += 256) hp[i] = 0u;
  for (int i = t; i < NBINS; i += 256) s[i] = 0.f;
  __syncthreads();  // publishes sb1 and zeroed LDS
  const unsigned b1v = sb1;

  double sgt = 0.0;
  const long long n8 = n >> 3;
  const float4* p4 = (const float4*)preds;
  const float4* t4 = (const float4*)gts;
  const long long NT = (long long)G2 * 256;  // compile-time stride
  const long long gtid = (long long)blockIdx.x * 256 + t;

#define PROC2(pp, tt)                                        \
  do {                                                       \
    float _v = poly1_val((pp), (tt));                        \
    unsigned _u = __float_as_uint(_v);                       \
    unsigned _b = _u >> 19;                                  \
    if (_b > b1v) {                                          \
      sgt += (double)_v;                                     \
    } else if (_b == b1v) {                                  \
      unsigned _k = (_u >> 7) & 0xFFFu;                      \
      atomicAdd(&hp[_k >> 1], (_k & 1u) ? 0x10000u : 1u);    \
      atomicAdd(&s[_k], _v);                                 \
    }                                                        \
  } while (0)

  for (long long i = gtid; i < n8; i += NT) {
    long long j = i << 1;
    float4 pa = p4[j], pb = p4[j + 1];
    float4 ta = t4[j], tb = t4[j + 1];
    PROC2(pa.x, ta.x); PROC2(pa.y, ta.y); PROC2(pa.z, ta.z); PROC2(pa.w, ta.w);
    PROC2(pb.x, tb.x); PROC2(pb.y, tb.y); PROC2(pb.z, tb.z); PROC2(pb.w, tb.w);
  }
  for (long long e = (n8 << 3) + gtid; e < n; e += NT) PROC2(preds[e], gts[e]);
#undef PROC2

#pragma unroll
  for (int off = 32; off; off >>= 1) sgt += __shfl_down(sgt, off, 64);
  if ((t & 63) == 0) wred[t >> 6] = sgt;
  __syncthreads();
  if (t == 0) blockSgt[blockIdx.x] = wred[0] + wred[1] + wred[2] + wred[3];

  unsigned int* hd = hist2R + (size_t)(blockIdx.x & (NREP2 - 1)) * NBINS;
  float* sd = sum2R + (size_t)(blockIdx.x & (NREP2 - 1)) * NBINS;
  for (int i = t; i < NBINS / 2; i += 256) {
    unsigned pw = hp[i];
    unsigned c0 = pw & 0xFFFFu, c1 = pw >> 16;
    if (c0) atomicAdd(&hd[2 * i + 0], c0);
    if (c1) atomicAdd(&hd[2 * i + 1], c1);
  }
  for (int i = t; i < NBINS; i += 256) {
    float sv = s[i];
    if (sv != 0.f) atomicAdd(&sd[i], sv);
  }
}

// ---------------- select2 + finalize: one block (R10 verbatim) -------------
__global__ void __launch_bounds__(1024) sel2fin_kernel(
    const Ctl* __restrict__ ctl, const unsigned int* __restrict__ hist2R,
    const float* __restrict__ sum2R, const double* __restrict__ blockSums,
    const double* __restrict__ blockSgt, float* __restrict__ out,
    unsigned int K) {
  __shared__ unsigned int chunk[1024];
  __shared__ double redsA[16], redsB[16], redsC[16];
  __shared__ double wfin[16][4];
  __shared__ unsigned int sb2, sr2;
  const int t = threadIdx.x;
  const unsigned K2 = ctl->r;  // remaining count needed from bucket b1 (>= 1)

  // ---- select2 within bucket b1 (fine bins t*4..t*4+3) ----
  unsigned hl[4];
  float sl[4];
  {
    uint4 hacc = {0u, 0u, 0u, 0u};
    float4 sacc = {0.f, 0.f, 0.f, 0.f};
    for (int r = 0; r < NREP2; ++r) {
      uint4 hv = *(const uint4*)&hist2R[(size_t)r * NBINS + t * 4];
      float4 sv = *(const float4*)&sum2R[(size_t)r * NBINS + t * 4];
      hacc.x += hv.x; hacc.y += hv.y; hacc.z += hv.z; hacc.w += hv.w;
      sacc.x += sv.x; sacc.y += sv.y; sacc.z += sv.z; sacc.w += sv.w;
    }
    hl[0] = hacc.x; hl[1] = hacc.y; hl[2] = hacc.z; hl[3] = hacc.w;
    sl[0] = sacc.x; sl[1] = sacc.y; sl[2] = sacc.z; sl[3] = sacc.w;
    chunk[t] = hacc.x + hacc.y + hacc.z + hacc.w;
  }
  __syncthreads();
  for (int off = 1; off < 1024; off <<= 1) {
    unsigned add = (t + off < 1024) ? chunk[t + off] : 0u;
    __syncthreads();
    chunk[t] += add;
    __syncthreads();
  }
  unsigned cum = (t < 1023) ? chunk[t + 1] : 0u;
  for (int j = 3; j >= 0; --j) {
    unsigned nc = cum + hl[j];
    if (cum < K2 && nc >= K2) { sb2 = (unsigned)(t * 4 + j); sr2 = K2 - cum; }
    cum = nc;
  }
  __syncthreads();
  const unsigned b2 = sb2, r2 = sr2;

  // exact sum of sub-buckets strictly above b2; b2's own count/sum
  double loc = 0.0, b2s = 0.0, b2c = 0.0;
#pragma unroll
  for (int j = 0; j < 4; ++j) {
    int bin = t * 4 + j;
    if (bin > (int)b2) loc += (double)sl[j];
    if (bin == (int)b2) { b2s = (double)sl[j]; b2c = (double)hl[j]; }
  }
#pragma unroll
  for (int off = 32; off; off >>= 1) {
    loc += __shfl_down(loc, off, 64);
    b2s += __shfl_down(b2s, off, 64);
    b2c += __shfl_down(b2c, off, 64);
  }
  if ((t & 63) == 0) { int w = t >> 6; redsA[w] = loc; redsB[w] = b2s; redsC[w] = b2c; }

  // ---- finalize: reduce per-block dice partials + Sgt ----
  double I = 0, Sp = 0, St = 0, Sg = 0;
  for (int i = t; i < G1; i += 1024) {
    I += blockSums[i * 3 + 0];
    Sp += blockSums[i * 3 + 1];
    St += blockSums[i * 3 + 2];
  }
  for (int i = t; i < G2; i += 1024) Sg += blockSgt[i];
#pragma unroll
  for (int off = 32; off; off >>= 1) {
    I += __shfl_down(I, off, 64);
    Sp += __shfl_down(Sp, off, 64);
    St += __shfl_down(St, off, 64);
    Sg += __shfl_down(Sg, off, 64);
  }
  if ((t & 63) == 0) {
    int w = t >> 6;
    wfin[w][0] = I; wfin[w][1] = Sp; wfin[w][2] = St; wfin[w][3] = Sg;
  }
  __syncthreads();
  if (t == 0) {
    double S2 = 0, bs = 0, bc = 0, tI = 0, tSp = 0, tSt = 0, tSg = 0;
#pragma unroll
    for (int w = 0; w < 16; ++w) {
      S2 += redsA[w]; bs += redsB[w]; bc += redsC[w];
      tI += wfin[w][0]; tSp += wfin[w][1]; tSt += wfin[w][2]; tSg += wfin[w][3];
    }
    // ties in sub-bucket b2 span < 128 ulps: bin average for the r2 remaining
    double topk_extra = S2 + (double)r2 * (bs / bc);
    double dice = 1.0 - (2.0 * tI + 1.0) / (tSp + tSt + 1.0);
    out[0] = (float)(dice + (tSg + topk_extra) / (double)K);
  }
}

extern "C" void kernel_launch(void* const* d_in, const int* in_sizes, int n_in,
                              void* d_out, int out_size, void* d_ws,
                              size_t ws_size, hipStream_t stream) {
  (void)n_in; (void)out_size; (void)ws_size;
  const float* preds = (const float*)d_in[0];
  const float* gts = (const float*)d_in[1];
  long long n = (long long)in_sizes[0];
  unsigned int K = (unsigned int)(n * 10 / 100);  // matches int(N*10/100)

  char* ws = (char*)d_ws;
  double* blockSums = (double*)ws;                     // G1*3*8 = 49152
  double* blockSgt = (double*)(ws + 49152);            // G2*8 = 12288 -> 61440
  Ctl* ctl = (Ctl*)(ws + 61440);                       // 64B, in zeroed region
  unsigned int* hist1R = (unsigned int*)(ws + 61504);  // NREP1*NBINS*4 = 131072
  unsigned int* hist2R = (unsigned int*)(ws + 192576); // NREP2*NBINS*4 = 65536
  float* sum2R = (float*)(ws + 258112);                // 65536 -> end 323648

  // zero ctl + replica region (contiguous, 256KB + 64B)
  (void)hipMemsetAsync(ws + 61440, 0, 262208, stream);

  pass1_kernel<<<G1, 256, 0, stream>>>(preds, gts, n, blockSums, hist1R);
  pass2_kernel<<<G2, 256, 0, stream>>>(preds, gts, n, K, hist1R, ctl,
                                       blockSgt, hist2R, sum2R);
  sel2fin_kernel<<<1, 1024, 0, stream>>>(ctl, hist2R, sum2R, blockSums,
                                         blockSgt, (float*)d_out, K);
}